// Round 3
// baseline (146.917 us; speedup 1.0000x reference)
//
#include <hip/hip_runtime.h>
#include <math.h>

// src (8,3,512,512) f32 | grid1 (8,32,8,16,16) f32 | grid2 (8,27,8,16,16) f32
// out (8,3,512,512) f32
#define BATCH 8
#define IMH 512
#define IMW 512
#define HWSZ (IMH * IMW)
#define XSPAN 9                // x-cells covered by one half-row block
#define CH 32                  // channels per cell in transposed layout (grid2 padded)
#define CPADH 40               // LDS cell stride in halves (80 B = 20 banks; 2-way max)
#define L_CELLS (XSPAN * 8)    // 72 (x,z) cells
#define LSLOTH (L_CELLS * CPADH)

typedef _Float16 half1;
typedef _Float16 half8 __attribute__((ext_vector_type(8)));

__device__ __forceinline__ float fast_tanh(float x) {
    float e = __expf(2.0f * x);
    return fmaf(-2.0f, __builtin_amdgcn_rcpf(e + 1.0f), 1.0f);
}

// ---- transpose+convert: grid1 -> t1 half [b][y][x][z][32], grid2 -> t2 half (ch 27..31 = 0)
__global__ __launch_bounds__(256) void transpose_both(const float* __restrict__ g1,
                                                      const float* __restrict__ g2,
                                                      half1* __restrict__ t1,
                                                      half1* __restrict__ t2) {
    int idx = blockIdx.x * 256 + threadIdx.x;  // 1,048,576 total
    if (idx < 524288) {                        // grid1 [b][c][z][y][x] linear read
        int x = idx & 15, y = (idx >> 4) & 15, z = (idx >> 8) & 7;
        int c = (idx >> 11) & 31, b = idx >> 16;
        t1[((((b * 16 + y) * 16 + x) * 8 + z) << 5) + c] = (half1)g1[idx];
    } else if (idx < 966656) {                 // grid2 (8*27*2048 = 442368)
        int j = idx - 524288;
        int x = j & 15, y = (j >> 4) & 15, z = (j >> 8) & 7;
        int r = j >> 11;
        int c = r % 27, b = r / 27;
        t2[((((b * 16 + y) * 16 + x) * 8 + z) << 5) + c] = (half1)g2[j];
    } else {                                   // zero 5 pad channels (16384 cells * 5)
        int k = idx - 966656;
        int cell = k / 5, p = k - cell * 5;
        t2[(cell << 5) + 27 + p] = (half1)0.0f;
    }
}

// ---- fused pipeline; one block = one half-row (256 pixels) of one batch image
template <bool TR>
__global__ __launch_bounds__(256, 4) void fused3(
    const float* __restrict__ src,
    const void* __restrict__ g1p,   // TR ? half[b][y][x][z][32] : raw f32 grid1
    const void* __restrict__ g2p,   // TR ? half[b][y][x][z][32] : raw f32 grid2
    const float* __restrict__ w1, const float* __restrict__ b1,
    const float* __restrict__ w2, const float* __restrict__ b2,
    const float* __restrict__ w3, const float* __restrict__ b3,
    const float* __restrict__ w4, const float* __restrict__ b4,
    float* __restrict__ out) {
    __shared__ __align__(16) half1 L1h[LSLOTH];  // y-lerped grid1 slab [x][z][40h]
    __shared__ __align__(16) half1 L2h[LSLOTH];  // y-lerped grid2 slab [x][z][40h]

    int tid = threadIdx.x;
    int half_ = blockIdx.x & 1;
    int h = (blockIdx.x >> 1) & 511;
    int b = blockIdx.x >> 10;
    int w0 = half_ << 8;
    int x_lo = half_ ? 7 : 0;

    float fy = (float)h * (15.0f / 512.0f);
    int y0 = (int)fy;
    float wy = fy - (float)y0;

    // ---------------- stage y-interpolated fp16 slabs into LDS ----------------
    if (TR) {
        half1 wyh = (half1)wy;
        const half1* t1h = (const half1*)g1p;
        const half1* t2h = (const half1*)g2p;
        // slab1: 9 cells * 8 z * 32 ch = 2304 halves = 288 half8 chunks
        {
            const half8* pa = (const half8*)(t1h + ((((size_t)b * 16 + y0) * 16 + x_lo) * 8) * CH);
            const half8* pb = pa + (16 * 8 * CH) / 8;  // next y row
            for (int t = tid; t < L_CELLS * 4; t += 256) {
                int g = t & 3, cell = t >> 2;
                half8 v0 = pa[t];
                half8 v1 = pb[t];
                half8 r = v0 + (v1 - v0) * wyh;
                *(half8*)&L1h[cell * CPADH + 8 * g] = r;
            }
        }
        {
            const half8* pa = (const half8*)(t2h + ((((size_t)b * 16 + y0) * 16 + x_lo) * 8) * CH);
            const half8* pb = pa + (16 * 8 * CH) / 8;
            for (int t = tid; t < L_CELLS * 4; t += 256) {
                int g = t & 3, cell = t >> 2;
                half8 v0 = pa[t];
                half8 v1 = pb[t];
                half8 r = v0 + (v1 - v0) * wyh;
                *(half8*)&L2h[cell * CPADH + 8 * g] = r;
            }
        }
    } else {  // fallback: scalar stage from raw fp32 grids (slow, correct)
        const float* g1f = (const float*)g1p;
        const float* g2f = (const float*)g2p;
        for (int t = tid; t < L_CELLS * CH; t += 256) {
            int c = t & 31, cell = t >> 5;
            int z = cell & 7, xj = cell >> 3;
            size_t o0 = ((((size_t)b * 32 + c) * 8 + z) * 16 + y0) * 16 + (x_lo + xj);
            float v0 = g1f[o0], v1 = g1f[o0 + 16];
            L1h[cell * CPADH + c] = (half1)fmaf(wy, v1 - v0, v0);
        }
        for (int t = tid; t < L_CELLS * CH; t += 256) {
            int c = t & 31, cell = t >> 5;
            int z = cell & 7, xj = cell >> 3;
            float v = 0.0f;
            if (c < 27) {
                size_t o0 = ((((size_t)b * 27 + c) * 8 + z) * 16 + y0) * 16 + (x_lo + xj);
                v = fmaf(wy, g2f[o0 + 16] - g2f[o0], g2f[o0]);
            }
            L2h[cell * CPADH + c] = (half1)v;
        }
    }
    __syncthreads();

    // ---------------- per-pixel pipeline ----------------
    int w = w0 + tid;
    const float* sb = src + (size_t)b * 3 * HWSZ + h * IMW + w;
    float s0 = sb[0];
    float s1 = sb[HWSZ];
    float s2 = sb[2 * HWSZ];

    // guide MLP #1: 3 -> 16 -> 1 (fp32)
    float acc = b2[0];
#pragma unroll
    for (int j = 0; j < 16; ++j) {
        float t = fmaf(w1[j * 3 + 0], s0,
                  fmaf(w1[j * 3 + 1], s1,
                  fmaf(w1[j * 3 + 2], s2, b1[j])));
        acc = fmaf(w2[j], fmaxf(t, 0.0f), acc);
    }
    float fz = fmaf(fast_tanh(acc), 3.5f, 3.5f);
    fz = fminf(fmaxf(fz, 0.0f), 7.0f);
    int z0 = min((int)fz, 6);
    float wz = fz - (float)z0;

    float fx = (float)w * (15.0f / 512.0f);
    int x0 = (int)fx;
    float wx = fx - (float)x0;
    int a00 = ((x0 - x_lo) * 8 + z0) * CPADH;

    float w11v = wx * wz;
    float w10v = wx - w11v;
    float w01v = wz - w11v;
    float w00v = 1.0f - wx - wz + w11v;
    half1 w00h = (half1)w00v, w01h = (half1)w01v, w10h = (half1)w10v, w11h = (half1)w11v;

    // slice 1: bilinear (x,z), packed fp16
    const half8* q00 = (const half8*)&L1h[a00];
    const half8* q01 = (const half8*)&L1h[a00 + CPADH];
    const half8* q10 = (const half8*)&L1h[a00 + 8 * CPADH];
    const half8* q11 = (const half8*)&L1h[a00 + 9 * CPADH];
    float c1f[32];
#pragma unroll
    for (int j = 0; j < 4; ++j) {
        half8 A = q00[j] * w00h + q01[j] * w01h + q10[j] * w10h + q11[j] * w11h;
#pragma unroll
        for (int k = 0; k < 8; ++k) c1f[j * 8 + k] = (float)A[k];
    }

    // affine #1: hidden = relu(coeff1 * src) (fp32)
    float hid[8];
#pragma unroll
    for (int o = 0; o < 8; ++o) {
        float t = fmaf(c1f[o], s0,
                  fmaf(c1f[8 + o], s1,
                  fmaf(c1f[16 + o], s2, c1f[24 + o])));
        hid[o] = fmaxf(t, 0.0f);
    }

    // guide MLP #2: 8 -> 16 -> 1 (fp32)
    float acc2 = b4[0];
#pragma unroll
    for (int j = 0; j < 16; ++j) {
        float t = b3[j];
#pragma unroll
        for (int i = 0; i < 8; ++i) t = fmaf(w3[j * 8 + i], hid[i], t);
        acc2 = fmaf(w4[j], fmaxf(t, 0.0f), acc2);
    }
    float fz2 = fmaf(fast_tanh(acc2), 3.5f, 3.5f);
    fz2 = fminf(fmaxf(fz2, 0.0f), 7.0f);
    int z0b = min((int)fz2, 6);
    float wz2 = fz2 - (float)z0b;

    int a00b = ((x0 - x_lo) * 8 + z0b) * CPADH;
    float u11 = wx * wz2;
    float u10 = wx - u11;
    float u01 = wz2 - u11;
    float u00 = 1.0f - wx - wz2 + u11;
    half1 u00h = (half1)u00, u01h = (half1)u01, u10h = (half1)u10, u11h = (half1)u11;

    // slice 2: bilinear (x,z), packed fp16 (27 real ch + 5 zero pad)
    const half8* r00 = (const half8*)&L2h[a00b];
    const half8* r01 = (const half8*)&L2h[a00b + CPADH];
    const half8* r10 = (const half8*)&L2h[a00b + 8 * CPADH];
    const half8* r11 = (const half8*)&L2h[a00b + 9 * CPADH];
    float c2f[27];
#pragma unroll
    for (int j = 0; j < 4; ++j) {
        half8 A = r00[j] * u00h + r01[j] * u01h + r10[j] * u10h + r11[j] * u11h;
#pragma unroll
        for (int k = 0; k < 8; ++k)
            if (j * 8 + k < 27) c2f[j * 8 + k] = (float)A[k];
    }

    // affine #2 (fp32)
    float* ob = out + (size_t)b * 3 * HWSZ + h * IMW + w;
#pragma unroll
    for (int o = 0; o < 3; ++o) {
        float t = c2f[24 + o];
#pragma unroll
        for (int i = 0; i < 8; ++i) t = fmaf(c2f[i * 3 + o], hid[i], t);
        ob[(size_t)o * HWSZ] = t;
    }
}

extern "C" void kernel_launch(void* const* d_in, const int* in_sizes, int n_in,
                              void* d_out, int out_size, void* d_ws, size_t ws_size,
                              hipStream_t stream) {
    const float* src   = (const float*)d_in[0];
    const float* grid1 = (const float*)d_in[1];
    const float* grid2 = (const float*)d_in[2];
    const float* w1 = (const float*)d_in[3];
    const float* b1 = (const float*)d_in[4];
    const float* w2 = (const float*)d_in[5];
    const float* b2 = (const float*)d_in[6];
    const float* w3 = (const float*)d_in[7];
    const float* b3 = (const float*)d_in[8];
    const float* w4 = (const float*)d_in[9];
    const float* b4 = (const float*)d_in[10];
    float* out = (float*)d_out;

    const size_t t_elems = (size_t)BATCH * 2048 * CH;     // 524288 halves each
    const size_t ws_needed = 2 * t_elems * sizeof(half1); // 2 MB

    const int nblk = (BATCH * HWSZ) / 256;                // 8192

    if (ws_size >= ws_needed) {
        half1* t1 = (half1*)d_ws;
        half1* t2 = t1 + t_elems;
        transpose_both<<<4096, 256, 0, stream>>>(grid1, grid2, t1, t2);
        fused3<true><<<nblk, 256, 0, stream>>>(
            src, t1, t2, w1, b1, w2, b2, w3, b3, w4, b4, out);
    } else {
        fused3<false><<<nblk, 256, 0, stream>>>(
            src, grid1, grid2, w1, b1, w2, b2, w3, b3, w4, b4, out);
    }
}

// Round 4
// 125.794 us; speedup vs baseline: 1.1679x; 1.1679x over previous
//
#include <hip/hip_runtime.h>
#include <math.h>

// src (8,3,512,512) f32 | grid1 (8,32,8,16,16) f32 | grid2 (8,27,8,16,16) f32
// out (8,3,512,512) f32
#define BATCH 8
#define IMH 512
#define IMW 512
#define HWSZ (IMH * IMW)
#define XSPAN 9                // x-cells covered by one half-row block
#define CH 32                  // channels per cell in transposed layout (grid2 padded)
#define CPADH 40               // LDS cell stride in halves (80 B: 16B-aligned, 20-bank stride)
#define L_CELLS (XSPAN * 8)    // 72 (x,z) cells
#define LSLOTH (L_CELLS * CPADH)

typedef _Float16 h1;
typedef _Float16 h2 __attribute__((ext_vector_type(2)));  // -> v_pk_* ops

union V16 {                    // one 16-byte LDS/global chunk = 8 halves = 4 h2
    uint4 u;
    h2 h[4];
};

__device__ __forceinline__ float fast_tanh(float x) {
    float e = __expf(2.0f * x);
    return fmaf(-2.0f, __builtin_amdgcn_rcpf(e + 1.0f), 1.0f);
}

// ---- transpose+convert: grid1 -> t1 half [b][y][x][z][32], grid2 -> t2 half (ch 27..31 = 0)
__global__ __launch_bounds__(256) void transpose_both(const float* __restrict__ g1,
                                                      const float* __restrict__ g2,
                                                      h1* __restrict__ t1,
                                                      h1* __restrict__ t2) {
    int idx = blockIdx.x * 256 + threadIdx.x;  // 1,048,576 total
    if (idx < 524288) {                        // grid1 [b][c][z][y][x] linear read
        int x = idx & 15, y = (idx >> 4) & 15, z = (idx >> 8) & 7;
        int c = (idx >> 11) & 31, b = idx >> 16;
        t1[((((b * 16 + y) * 16 + x) * 8 + z) << 5) + c] = (h1)g1[idx];
    } else if (idx < 966656) {                 // grid2 (8*27*2048 = 442368)
        int j = idx - 524288;
        int x = j & 15, y = (j >> 4) & 15, z = (j >> 8) & 7;
        int r = j >> 11;
        int c = r % 27, b = r / 27;
        t2[((((b * 16 + y) * 16 + x) * 8 + z) << 5) + c] = (h1)g2[j];
    } else {                                   // zero 5 pad channels (16384 cells * 5)
        int k = idx - 966656;
        int cell = k / 5, p = k - cell * 5;
        t2[(cell << 5) + 27 + p] = (h1)0.0f;
    }
}

// ---- fused pipeline; one block = one half-row (256 pixels) of one batch image
template <bool TR>
__global__ __launch_bounds__(256, 4) void fused4(
    const float* __restrict__ src,
    const void* __restrict__ g1p,   // TR ? half[b][y][x][z][32] : raw f32 grid1
    const void* __restrict__ g2p,
    const float* __restrict__ w1, const float* __restrict__ b1,
    const float* __restrict__ w2, const float* __restrict__ b2,
    const float* __restrict__ w3, const float* __restrict__ b3,
    const float* __restrict__ w4, const float* __restrict__ b4,
    float* __restrict__ out) {
    __shared__ __align__(16) h1 L1h[LSLOTH];  // y-lerped grid1 slab [x][z][40h]
    __shared__ __align__(16) h1 L2h[LSLOTH];  // y-lerped grid2 slab [x][z][40h]

    int tid = threadIdx.x;
    int half_ = blockIdx.x & 1;
    int h = (blockIdx.x >> 1) & 511;
    int b = blockIdx.x >> 10;
    int w0 = half_ << 8;
    int x_lo = half_ ? 7 : 0;

    float fy = (float)h * (15.0f / 512.0f);
    int y0 = (int)fy;
    float wy = fy - (float)y0;

    // ---------------- stage y-interpolated fp16 slabs into LDS (packed math) ----------------
    if (TR) {
        h2 wyh = (h2)(h1)wy;   // splat
        {
            const uint4* pa = (const uint4*)((const h1*)g1p +
                              ((((size_t)b * 16 + y0) * 16 + x_lo) * 8) * CH);
            const uint4* pb = pa + (16 * 8 * CH) / 8;  // next y row
            for (int t = tid; t < L_CELLS * 4; t += 256) {  // 288 chunks
                int g = t & 3, cell = t >> 2;
                V16 v0, v1, r;
                v0.u = pa[t];
                v1.u = pb[t];
#pragma unroll
                for (int k = 0; k < 4; ++k) r.h[k] = v0.h[k] + (v1.h[k] - v0.h[k]) * wyh;
                *(uint4*)&L1h[cell * CPADH + 8 * g] = r.u;
            }
        }
        {
            const uint4* pa = (const uint4*)((const h1*)g2p +
                              ((((size_t)b * 16 + y0) * 16 + x_lo) * 8) * CH);
            const uint4* pb = pa + (16 * 8 * CH) / 8;
            for (int t = tid; t < L_CELLS * 4; t += 256) {
                int g = t & 3, cell = t >> 2;
                V16 v0, v1, r;
                v0.u = pa[t];
                v1.u = pb[t];
#pragma unroll
                for (int k = 0; k < 4; ++k) r.h[k] = v0.h[k] + (v1.h[k] - v0.h[k]) * wyh;
                *(uint4*)&L2h[cell * CPADH + 8 * g] = r.u;
            }
        }
    } else {  // fallback: scalar stage from raw fp32 grids (slow, correct)
        const float* g1f = (const float*)g1p;
        const float* g2f = (const float*)g2p;
        for (int t = tid; t < L_CELLS * CH; t += 256) {
            int c = t & 31, cell = t >> 5;
            int z = cell & 7, xj = cell >> 3;
            size_t o0 = ((((size_t)b * 32 + c) * 8 + z) * 16 + y0) * 16 + (x_lo + xj);
            float v0 = g1f[o0], v1 = g1f[o0 + 16];
            L1h[cell * CPADH + c] = (h1)fmaf(wy, v1 - v0, v0);
        }
        for (int t = tid; t < L_CELLS * CH; t += 256) {
            int c = t & 31, cell = t >> 5;
            int z = cell & 7, xj = cell >> 3;
            float v = 0.0f;
            if (c < 27) {
                size_t o0 = ((((size_t)b * 27 + c) * 8 + z) * 16 + y0) * 16 + (x_lo + xj);
                v = fmaf(wy, g2f[o0 + 16] - g2f[o0], g2f[o0]);
            }
            L2h[cell * CPADH + c] = (h1)v;
        }
    }
    __syncthreads();

    // ---------------- per-pixel pipeline ----------------
    int w = w0 + tid;
    const float* sb = src + (size_t)b * 3 * HWSZ + h * IMW + w;
    float s0 = sb[0];
    float s1 = sb[HWSZ];
    float s2 = sb[2 * HWSZ];

    // guide MLP #1: 3 -> 16 -> 1 (fp32)
    float acc = b2[0];
#pragma unroll
    for (int j = 0; j < 16; ++j) {
        float t = fmaf(w1[j * 3 + 0], s0,
                  fmaf(w1[j * 3 + 1], s1,
                  fmaf(w1[j * 3 + 2], s2, b1[j])));
        acc = fmaf(w2[j], fmaxf(t, 0.0f), acc);
    }
    float fz = fmaf(fast_tanh(acc), 3.5f, 3.5f);
    fz = fminf(fmaxf(fz, 0.0f), 7.0f);
    int z0 = min((int)fz, 6);
    float wz = fz - (float)z0;

    float fx = (float)w * (15.0f / 512.0f);
    int x0 = (int)fx;
    float wx = fx - (float)x0;
    int a00 = ((x0 - x_lo) * 8 + z0) * CPADH;

    float w11v = wx * wz;
    float w10v = wx - w11v;
    float w01v = wz - w11v;
    float w00v = 1.0f - wx - wz + w11v;
    h2 W00 = (h2)(h1)w00v, W01 = (h2)(h1)w01v, W10 = (h2)(h1)w10v, W11 = (h2)(h1)w11v;

    // slice 1: bilinear (x,z) over 32 ch, packed fp16 (mul + 3 fma per h2)
    const uint4* p00 = (const uint4*)&L1h[a00];
    const uint4* p01 = (const uint4*)&L1h[a00 + CPADH];
    const uint4* p10 = (const uint4*)&L1h[a00 + 8 * CPADH];
    const uint4* p11 = (const uint4*)&L1h[a00 + 9 * CPADH];
    float c1f[32];
#pragma unroll
    for (int j = 0; j < 4; ++j) {
        V16 A, B, C, D;
        A.u = p00[j];
        B.u = p01[j];
        C.u = p10[j];
        D.u = p11[j];
#pragma unroll
        for (int k = 0; k < 4; ++k) {
            h2 r = A.h[k] * W00 + B.h[k] * W01 + C.h[k] * W10 + D.h[k] * W11;
            c1f[j * 8 + 2 * k]     = (float)r[0];
            c1f[j * 8 + 2 * k + 1] = (float)r[1];
        }
    }

    // affine #1: hidden = relu(coeff1 * src) (fp32)
    float hid[8];
#pragma unroll
    for (int o = 0; o < 8; ++o) {
        float t = fmaf(c1f[o], s0,
                  fmaf(c1f[8 + o], s1,
                  fmaf(c1f[16 + o], s2, c1f[24 + o])));
        hid[o] = fmaxf(t, 0.0f);
    }

    // guide MLP #2: 8 -> 16 -> 1 (fp32)
    float acc2 = b4[0];
#pragma unroll
    for (int j = 0; j < 16; ++j) {
        float t = b3[j];
#pragma unroll
        for (int i = 0; i < 8; ++i) t = fmaf(w3[j * 8 + i], hid[i], t);
        acc2 = fmaf(w4[j], fmaxf(t, 0.0f), acc2);
    }
    float fz2 = fmaf(fast_tanh(acc2), 3.5f, 3.5f);
    fz2 = fminf(fmaxf(fz2, 0.0f), 7.0f);
    int z0b = min((int)fz2, 6);
    float wz2 = fz2 - (float)z0b;

    int a00b = ((x0 - x_lo) * 8 + z0b) * CPADH;
    float u11 = wx * wz2;
    float u10 = wx - u11;
    float u01 = wz2 - u11;
    float u00 = 1.0f - wx - wz2 + u11;
    h2 U00 = (h2)(h1)u00, U01 = (h2)(h1)u01, U10 = (h2)(h1)u10, U11 = (h2)(h1)u11;

    // slice 2: bilinear (x,z) over 27 real ch (+5 zero pad), packed fp16
    const uint4* q00 = (const uint4*)&L2h[a00b];
    const uint4* q01 = (const uint4*)&L2h[a00b + CPADH];
    const uint4* q10 = (const uint4*)&L2h[a00b + 8 * CPADH];
    const uint4* q11 = (const uint4*)&L2h[a00b + 9 * CPADH];
    float c2f[27];
#pragma unroll
    for (int j = 0; j < 4; ++j) {
        V16 A, B, C, D;
        A.u = q00[j];
        B.u = q01[j];
        C.u = q10[j];
        D.u = q11[j];
#pragma unroll
        for (int k = 0; k < 4; ++k) {
            h2 r = A.h[k] * U00 + B.h[k] * U01 + C.h[k] * U10 + D.h[k] * U11;
            int c = j * 8 + 2 * k;
            if (c < 27)     c2f[c]     = (float)r[0];
            if (c + 1 < 27) c2f[c + 1] = (float)r[1];
        }
    }

    // affine #2 (fp32)
    float* ob = out + (size_t)b * 3 * HWSZ + h * IMW + w;
#pragma unroll
    for (int o = 0; o < 3; ++o) {
        float t = c2f[24 + o];
#pragma unroll
        for (int i = 0; i < 8; ++i) t = fmaf(c2f[i * 3 + o], hid[i], t);
        ob[(size_t)o * HWSZ] = t;
    }
}

extern "C" void kernel_launch(void* const* d_in, const int* in_sizes, int n_in,
                              void* d_out, int out_size, void* d_ws, size_t ws_size,
                              hipStream_t stream) {
    const float* src   = (const float*)d_in[0];
    const float* grid1 = (const float*)d_in[1];
    const float* grid2 = (const float*)d_in[2];
    const float* w1 = (const float*)d_in[3];
    const float* b1 = (const float*)d_in[4];
    const float* w2 = (const float*)d_in[5];
    const float* b2 = (const float*)d_in[6];
    const float* w3 = (const float*)d_in[7];
    const float* b3 = (const float*)d_in[8];
    const float* w4 = (const float*)d_in[9];
    const float* b4 = (const float*)d_in[10];
    float* out = (float*)d_out;

    const size_t t_elems = (size_t)BATCH * 2048 * CH;     // 524288 halves each
    const size_t ws_needed = 2 * t_elems * sizeof(h1);    // 2 MB

    const int nblk = (BATCH * HWSZ) / 256;                // 8192

    if (ws_size >= ws_needed) {
        h1* t1 = (h1*)d_ws;
        h1* t2 = t1 + t_elems;
        transpose_both<<<4096, 256, 0, stream>>>(grid1, grid2, t1, t2);
        fused4<true><<<nblk, 256, 0, stream>>>(
            src, t1, t2, w1, b1, w2, b2, w3, b3, w4, b4, out);
    } else {
        fused4<false><<<nblk, 256, 0, stream>>>(
            src, grid1, grid2, w1, b1, w2, b2, w3, b3, w4, b4, out);
    }
}